// Round 8
// baseline (441.317 us; speedup 1.0000x reference)
//
#include <hip/hip_runtime.h>
#include <stdint.h>

#define NB 8
#define NC 256
#define NE 128
#define NHW 4096

typedef __bf16 v8bf __attribute__((ext_vector_type(8)));
typedef float v4f __attribute__((ext_vector_type(4)));
typedef float v16f __attribute__((ext_vector_type(16)));
typedef unsigned int v4u __attribute__((ext_vector_type(4)));

#if __has_builtin(__builtin_amdgcn_exp2f)
#define EXP2F(x) __builtin_amdgcn_exp2f(x)
#else
#define EXP2F(x) exp2f(x)
#endif

// fp32 -> bf16 round-to-nearest-even (bit trick; finite inputs only)
__device__ __forceinline__ unsigned short f2bf(float x) {
    union { float f; unsigned int u; } v; v.f = x;
    unsigned int r = v.u + 0x7fffu + ((v.u >> 16) & 1u);
    return (unsigned short)(r >> 16);
}

// pack two fp32 -> bf16x2, round-half-up (5 VALU per pair; fine for P in (0,1], R4-verified)
__device__ __forceinline__ unsigned int pack_bf2_ru(float a, float b) {
    union { float f; unsigned int u; } va, vb; va.f = a; vb.f = b;
    return ((va.u + 0x8000u) >> 16) | ((vb.u + 0x8000u) & 0xffff0000u);
}

// ---------------- K0: cast weights to bf16. Wbf[e][c], e<128 = w_theta * (scale*log2e), e>=128 = w_phi
__global__ __launch_bounds__(256) void cast_w_kernel(const float* __restrict__ wt,
                                                     const float* __restrict__ wp,
                                                     unsigned short* __restrict__ Wbf) {
    int i = blockIdx.x * 256 + threadIdx.x;                 // 0..65535
    const float QS = 0.08838834764831845f * 1.4426950408889634f; // 1/sqrt(128) * log2(e)
    float v = (i < 32768) ? wt[i] * QS : wp[i - 32768];
    Wbf[i] = f2bf(v);
}

// ---------------- K1: projection (+ fused V cast). Per block: batch b, 64-q tile.
__global__ __launch_bounds__(256, 2) void proj_kernel(const float* __restrict__ l,
                                                      const unsigned short* __restrict__ Wbf,
                                                      unsigned short* __restrict__ Qbf,
                                                      unsigned short* __restrict__ Kbf,
                                                      unsigned short* __restrict__ Vbf) {
    __shared__ __align__(16) unsigned short A[64][264];     // [q][c], +8 pad
    __shared__ __align__(16) unsigned short Ost[2][32][136];// out staging
    const int tid = threadIdx.x;
    const int b = blockIdx.x & 7;
    const int qt = (blockIdx.x >> 3) << 6;
    const float* lb = l + ((size_t)b * NC * NHW + qt);

    for (int s = 0; s < 16; ++s) {
        int f = tid + s * 256;
        int c = f >> 4, j = f & 15;
        float4 v = *(const float4*)(lb + (size_t)c * NHW + j * 4);
        ushort4 o4;
        o4.x = f2bf(v.x); o4.y = f2bf(v.y); o4.z = f2bf(v.z); o4.w = f2bf(v.w);
        A[j * 4 + 0][c] = o4.x;
        A[j * 4 + 1][c] = o4.y;
        A[j * 4 + 2][c] = o4.z;
        A[j * 4 + 3][c] = o4.w;
        *(ushort4*)(Vbf + (size_t)b * NC * NHW + (size_t)c * NHW + qt + j * 4) = o4;
    }
    __syncthreads();

    const int w = tid >> 6, L = tid & 63;
    const int l15 = L & 15, q4 = L >> 4;
    const v4f vz = {0.f, 0.f, 0.f, 0.f};
    v4f acc[4][4];
    for (int mt = 0; mt < 4; ++mt)
        for (int nt = 0; nt < 4; ++nt) acc[mt][nt] = vz;

    for (int kf = 0; kf < 8; ++kf) {
        int kc = kf * 32 + q4 * 8;
        v8bf a[4], bb[4];
        for (int mt = 0; mt < 4; ++mt)
            a[mt] = *(const v8bf*)&A[mt * 16 + l15][kc];
        for (int nt = 0; nt < 4; ++nt)
            bb[nt] = *(const v8bf*)(Wbf + (w * 64 + nt * 16 + l15) * 256 + kc);
        for (int mt = 0; mt < 4; ++mt)
            for (int nt = 0; nt < 4; ++nt)
                acc[mt][nt] = __builtin_amdgcn_mfma_f32_16x16x32_bf16(a[mt], bb[nt], acc[mt][nt], 0, 0, 0);
    }

    // epilogue: 2 phases of 32 q-rows; LDS transpose -> coalesced dwordx4 stores
    const int side = w >> 1;
    const int ebase = (w & 1) * 64;
#pragma unroll
    for (int ph = 0; ph < 2; ++ph) {
        __syncthreads();
#pragma unroll
        for (int mh = 0; mh < 2; ++mh) {
            int mt = ph * 2 + mh;
#pragma unroll
            for (int nt = 0; nt < 4; ++nt)
#pragma unroll
                for (int r = 0; r < 4; ++r) {
                    int q32 = mh * 16 + q4 * 4 + r;
                    Ost[side][q32][ebase + nt * 16 + l15] = f2bf(acc[mt][nt][r]);
                }
        }
        __syncthreads();
#pragma unroll
        for (int s = 0; s < 4; ++s) {
            int idx = tid + s * 256;
            int sd = idx >> 9, rem = idx & 511;
            int r32 = rem >> 4, c8 = rem & 15;
            unsigned short* dst = sd ? Kbf : Qbf;
            *(uint4*)(dst + ((size_t)b * NHW + qt + ph * 32 + r32) * NE + c8 * 8) =
                *(const uint4*)&Ost[sd][r32][c8 * 8];
        }
    }
}

// ---------------- K2: flash attention -- BARRIER-FREE, LDS-FREE per-wave design.
// Each wave owns a 32-q slice and iterates ALL k (128 tiles of 32):
//   S^T = K*Q^T   A=K global frags (R6-verified layout), B=Q regs, C/D lane=q-col
//   P^T built in registers via lane^32 exchange (R3-verified assembly)
//   O^T += V*P^T  A=V global frags (R6-verified), B=P^T regs; o = 8x v16f (128 AGPR)
// No inter-wave communication at all -> no syncthreads; a bare s_barrier (no
// waitcnt) paces the block's 4 waves so they share K/V tiles through L1
// (24KB/iter working set < 32KB L1). K/V frags consume-then-reload (R7 pattern)
// -> ~1 iter of prefetch slack. 1 wave/SIMD (512-reg budget) -> pure-ILP.
__global__ __launch_bounds__(256, 1) void attn_kernel(const unsigned short* __restrict__ Qbf,
                                                      const unsigned short* __restrict__ Kbf,
                                                      const unsigned short* __restrict__ Vbf,
                                                      float* __restrict__ out) {
    const int tid = threadIdx.x;
    const int b = blockIdx.x & 7;                           // batch -> XCD affinity
    const int q128 = (blockIdx.x >> 3) << 7;                // 128-q tile per block
    const int w = tid >> 6;
    const int L = tid & 63;
    const int l31 = L & 31, hi = L >> 5;

    const unsigned short* Kb = Kbf + (size_t)b * NHW * NE;
    const unsigned short* Vb = Vbf + (size_t)b * NC * NHW;

    // Q B-frags (whole kernel): B[k=e][n=q], lane n = q = q128 + w*32 + l31
    v8bf bq[8];
    {
        const unsigned short* qrow = Qbf + ((size_t)b * NHW + q128 + w * 32 + l31) * NE + hi * 8;
#pragma unroll
        for (int ef = 0; ef < 8; ++ef)
            bq[ef] = *(const v8bf*)(qrow + ef * 16);
    }

    // K A-frag base: row = k0 + l31, 16B chunk (2ef+hi) -> ak[ef] = kbase + k0*NE + ef*16
    const unsigned short* kbase = Kb + (size_t)l31 * NE + hi * 8;
    // V A-frag base: row c = ct*32 + l31, chunk (2kf+hi) -> av = vbase + ct*32*NHW + k0 + kf*16
    const unsigned short* vbase = Vb + (size_t)l31 * NHW + hi * 8;

    v16f o[8];
#pragma unroll
    for (int ct = 0; ct < 8; ++ct)
#pragma unroll
        for (int r = 0; r < 16; ++r) o[ct][r] = 0.f;
    float lacc = 0.f;

    // ---- prologue: frags for tile 0
    v8bf ak[8], av[8][2];
#pragma unroll
    for (int ef = 0; ef < 8; ++ef)
        ak[ef] = *(const v8bf*)(kbase + ef * 16);
#pragma unroll
    for (int ct = 0; ct < 8; ++ct) {
        av[ct][0] = *(const v8bf*)(vbase + (size_t)ct * 32 * NHW);
        av[ct][1] = *(const v8bf*)(vbase + (size_t)ct * 32 * NHW + 16);
    }

    for (int it = 0; it < 128; ++it) {
        const size_t kn = (size_t)((it + 1) & 127) * 32;    // next tile k-offset
        // pacing barrier ONLY (no waitcnt -> prefetch stays in flight; no shared
        // state -> no memory semantics needed). Keeps 4 waves L1-coherent.
        asm volatile("s_barrier" ::: "memory");

        // ---- QK: S^T[32k][32q]; two independent 4-deep chains
        v16f sa, sb;
#pragma unroll
        for (int r = 0; r < 16; ++r) { sa[r] = 0.f; sb[r] = 0.f; }
#pragma unroll
        for (int ef = 0; ef < 4; ++ef) {
            sa = __builtin_amdgcn_mfma_f32_32x32x16_bf16(ak[2 * ef], bq[2 * ef], sa, 0, 0, 0);
            sb = __builtin_amdgcn_mfma_f32_32x32x16_bf16(ak[2 * ef + 1], bq[2 * ef + 1], sb, 0, 0, 0);
        }
        // reload K frags for next tile (consumed above; slack = softmax + PV)
#pragma unroll
        for (int ef = 0; ef < 8; ++ef)
            ak[ef] = *(const v8bf*)(kbase + kn * NE + ef * 16);

        // ---- softmax: p = 2^s (scale*log2e folded into Q); lane owns one q-col
        float p[16];
#pragma unroll
        for (int r = 0; r < 16; ++r) p[r] = EXP2F(sa[r] + sb[r]);
#pragma unroll
        for (int r = 0; r < 16; ++r) lacc += p[r];

        // ---- P^T B-frags in regs (R3-verified lane^32 exchange):
        // f0 covers k rows 0-15 of this tile, f1 covers 16-31; lane n = q-col.
        unsigned int pk[8], px[8];
#pragma unroll
        for (int t = 0; t < 8; ++t) pk[t] = pack_bf2_ru(p[2 * t], p[2 * t + 1]);
#pragma unroll
        for (int t = 0; t < 8; ++t) px[t] = (unsigned int)__shfl_xor((int)pk[t], 32);
        union { v4u u; v8bf b; } f0, f1;
        if (hi == 0) {
            f0.u = (v4u){pk[0], pk[1], px[0], px[1]};
            f1.u = (v4u){pk[4], pk[5], px[4], px[5]};
        } else {
            f0.u = (v4u){px[2], px[3], pk[2], pk[3]};
            f1.u = (v4u){px[6], px[7], pk[6], pk[7]};
        }

        // ---- PV: O^T[c][q] += V * P^T; 16 MFMAs, 8 independent chains (kf outer)
#pragma unroll
        for (int ct = 0; ct < 8; ++ct)
            o[ct] = __builtin_amdgcn_mfma_f32_32x32x16_bf16(av[ct][0], f0.b, o[ct], 0, 0, 0);
#pragma unroll
        for (int ct = 0; ct < 8; ++ct)
            o[ct] = __builtin_amdgcn_mfma_f32_32x32x16_bf16(av[ct][1], f1.b, o[ct], 0, 0, 0);
        // reload V frags for next tile (slack = next barrier + QK + softmax)
#pragma unroll
        for (int ct = 0; ct < 8; ++ct) {
            av[ct][0] = *(const v8bf*)(vbase + (size_t)ct * 32 * NHW + kn);
            av[ct][1] = *(const v8bf*)(vbase + (size_t)ct * 32 * NHW + kn + 16);
        }
    }

    // ---- epilogue (no LDS, no barrier): full k-sum = own half + partner half
    const float inv = 1.0f / (lacc + __shfl_xor(lacc, 32));

    // store: O^T C/D lane = q-col -> out[b][c][q128 + w*32 + l31], coalesced dwords
    float* ob = out + (size_t)b * NC * NHW + q128 + w * 32 + l31;
#pragma unroll
    for (int ct = 0; ct < 8; ++ct)
#pragma unroll
        for (int r = 0; r < 16; ++r) {
            int c = ct * 32 + (r & 3) + 8 * (r >> 2) + 4 * hi;
            ob[(size_t)c * NHW] = o[ct][r] * inv;
        }
}

extern "C" void kernel_launch(void* const* d_in, const int* in_sizes, int n_in,
                              void* d_out, int out_size, void* d_ws, size_t ws_size,
                              hipStream_t stream) {
    const float* l  = (const float*)d_in[0];
    const float* wt = (const float*)d_in[1];
    const float* wp = (const float*)d_in[2];
    float* out = (float*)d_out;

    char* ws = (char*)d_ws;
    unsigned short* Wbf = (unsigned short*)ws;                          // 131072 B
    unsigned short* Qbf = (unsigned short*)(ws + 131072);               // 8 MB
    unsigned short* Kbf = (unsigned short*)(ws + 131072 + 8388608);     // 8 MB
    unsigned short* Vbf = (unsigned short*)(ws + 131072 + 16777216);    // 16 MB

    hipLaunchKernelGGL(cast_w_kernel, dim3(256), dim3(256), 0, stream, wt, wp, Wbf);
    hipLaunchKernelGGL(proj_kernel,   dim3(512), dim3(256), 0, stream, l, Wbf, Qbf, Kbf, Vbf);
    hipLaunchKernelGGL(attn_kernel,   dim3(256), dim3(256), 0, stream, Qbf, Kbf, Vbf, out);
}

// Round 9
// 218.088 us; speedup vs baseline: 2.0236x; 2.0236x over previous
//
#include <hip/hip_runtime.h>
#include <stdint.h>

#define NB 8
#define NC 256
#define NE 128
#define NHW 4096

typedef __bf16 v8bf __attribute__((ext_vector_type(8)));
typedef float v4f __attribute__((ext_vector_type(4)));
typedef float v16f __attribute__((ext_vector_type(16)));
typedef unsigned int v4u __attribute__((ext_vector_type(4)));

typedef unsigned int __attribute__((address_space(1))) uint_g;
typedef unsigned int __attribute__((address_space(3))) uint_l;

#if __has_builtin(__builtin_amdgcn_exp2f)
#define EXP2F(x) __builtin_amdgcn_exp2f(x)
#else
#define EXP2F(x) exp2f(x)
#endif

// LDS-only barrier: drains lgkmcnt but NOT vmcnt (global prefetch/DMA stays in flight)
#define BARRIER_LDS() asm volatile("s_waitcnt lgkmcnt(0)\n\ts_barrier" ::: "memory")
#define WAIT_VM0()    asm volatile("s_waitcnt vmcnt(0)" ::: "memory")

// async global->LDS DMA, 16B per lane: LDS dst = uniform base + lane*16
__device__ __forceinline__ void dma16(const unsigned short* g, unsigned short* l) {
    __builtin_amdgcn_global_load_lds((const uint_g*)g, (uint_l*)l, 16, 0, 0);
}

// fp32 -> bf16 round-to-nearest-even
__device__ __forceinline__ unsigned short f2bf(float x) {
    union { float f; unsigned int u; } v; v.f = x;
    unsigned int r = v.u + 0x7fffu + ((v.u >> 16) & 1u);
    return (unsigned short)(r >> 16);
}

// pack two fp32 -> bf16x2, round-half-up (P in (0,1], R4-verified accuracy)
__device__ __forceinline__ unsigned int pack_bf2_ru(float a, float b) {
    union { float f; unsigned int u; } va, vb; va.f = a; vb.f = b;
    return ((va.u + 0x8000u) >> 16) | ((vb.u + 0x8000u) & 0xffff0000u);
}

// ---------------- K0: cast weights. Wbf[e][c], e<128 = w_theta*(scale*log2e), e>=128 = w_phi
__global__ __launch_bounds__(256) void cast_w_kernel(const float* __restrict__ wt,
                                                     const float* __restrict__ wp,
                                                     unsigned short* __restrict__ Wbf) {
    int i = blockIdx.x * 256 + threadIdx.x;
    const float QS = 0.08838834764831845f * 1.4426950408889634f;
    float v = (i < 32768) ? wt[i] * QS : wp[i - 32768];
    Wbf[i] = f2bf(v);
}

// ---------------- K1: projection (+ fused V cast). K is stored PRE-SWIZZLED
// (16B unit u at position u ^ (row&15) within each row) so attn's LDS DMA copy
// is read conflict-free with the R5-verified fragment pattern. Q unswizzled.
__global__ __launch_bounds__(256, 2) void proj_kernel(const float* __restrict__ l,
                                                      const unsigned short* __restrict__ Wbf,
                                                      unsigned short* __restrict__ Qbf,
                                                      unsigned short* __restrict__ Kbf,
                                                      unsigned short* __restrict__ Vbf) {
    __shared__ __align__(16) unsigned short A[64][264];
    __shared__ __align__(16) unsigned short Ost[2][32][136];
    const int tid = threadIdx.x;
    const int b = blockIdx.x & 7;
    const int qt = (blockIdx.x >> 3) << 6;
    const float* lb = l + ((size_t)b * NC * NHW + qt);

    for (int s = 0; s < 16; ++s) {
        int f = tid + s * 256;
        int c = f >> 4, j = f & 15;
        float4 v = *(const float4*)(lb + (size_t)c * NHW + j * 4);
        ushort4 o4;
        o4.x = f2bf(v.x); o4.y = f2bf(v.y); o4.z = f2bf(v.z); o4.w = f2bf(v.w);
        A[j * 4 + 0][c] = o4.x;
        A[j * 4 + 1][c] = o4.y;
        A[j * 4 + 2][c] = o4.z;
        A[j * 4 + 3][c] = o4.w;
        *(ushort4*)(Vbf + (size_t)b * NC * NHW + (size_t)c * NHW + qt + j * 4) = o4;
    }
    __syncthreads();

    const int w = tid >> 6, L = tid & 63;
    const int l15 = L & 15, q4 = L >> 4;
    const v4f vz = {0.f, 0.f, 0.f, 0.f};
    v4f acc[4][4];
    for (int mt = 0; mt < 4; ++mt)
        for (int nt = 0; nt < 4; ++nt) acc[mt][nt] = vz;

    for (int kf = 0; kf < 8; ++kf) {
        int kc = kf * 32 + q4 * 8;
        v8bf a[4], bb[4];
        for (int mt = 0; mt < 4; ++mt)
            a[mt] = *(const v8bf*)&A[mt * 16 + l15][kc];
        for (int nt = 0; nt < 4; ++nt)
            bb[nt] = *(const v8bf*)(Wbf + (w * 64 + nt * 16 + l15) * 256 + kc);
        for (int mt = 0; mt < 4; ++mt)
            for (int nt = 0; nt < 4; ++nt)
                acc[mt][nt] = __builtin_amdgcn_mfma_f32_16x16x32_bf16(a[mt], bb[nt], acc[mt][nt], 0, 0, 0);
    }

    const int side = w >> 1;
    const int ebase = (w & 1) * 64;
#pragma unroll
    for (int ph = 0; ph < 2; ++ph) {
        __syncthreads();
#pragma unroll
        for (int mh = 0; mh < 2; ++mh) {
            int mt = ph * 2 + mh;
#pragma unroll
            for (int nt = 0; nt < 4; ++nt)
#pragma unroll
                for (int r = 0; r < 4; ++r) {
                    int q32 = mh * 16 + q4 * 4 + r;
                    Ost[side][q32][ebase + nt * 16 + l15] = f2bf(acc[mt][nt][r]);
                }
        }
        __syncthreads();
#pragma unroll
        for (int s = 0; s < 4; ++s) {
            int idx = tid + s * 256;
            int sd = idx >> 9, rem = idx & 511;
            int r32 = rem >> 4, c8 = rem & 15;
            unsigned short* dst = sd ? Kbf : Qbf;
            int c8s = sd ? (c8 ^ (r32 & 15)) : c8;   // pre-swizzle K only
            *(uint4*)(dst + ((size_t)b * NHW + qt + ph * 32 + r32) * NE + c8s * 8) =
                *(const uint4*)&Ost[sd][r32][c8 * 8];
        }
    }
}

// ---------------- K2: flash attention, producer/consumer wave specialization.
// Block 512 thr = 8 waves, q-tile 128, k-tile 64, 65 rounds, 1 LDS-only barrier/round.
// Waves 0-3 (SIMD 0-3) PRODUCE: round i: QK S^T[64k x 32q] (16 MFMA, A=K from
//   DMA'd LDS, B=Q regs) -> softmax -> in-reg P^T B-frags (R3-verified lane^32
//   exchange) -> 4 conflict-free ds_write_b128 into Pu[buf i&1].
// Waves 4-7 (SIMD 0-3) CONSUME: round i: PV O^T[64c x 128q] (32 MFMA, A=V
//   global-direct frags (R6-verified), B=P^T from Pu[buf (i-1)&1]).
// K feed: __builtin_amdgcn_global_load_lds dbuf; producers vmcnt(0) before the
// round barrier (full-round slack). Each SIMD: 1P+1C -> QK/softmax/PV always
// overlapped; matrix pipe demand 48 MFMA * 32cyc = 1536 cyc/round/SIMD.
// LDS: Ku dbuf 32K | Pu dbuf 32K | lsum 512B.
__global__ __launch_bounds__(512, 2) void attn_kernel(const unsigned short* __restrict__ Qbf,
                                                      const unsigned short* __restrict__ Kbf,
                                                      const unsigned short* __restrict__ Vbf,
                                                      float* __restrict__ out) {
    __shared__ __align__(16) unsigned char smem[66048];
    unsigned short* KuS = (unsigned short*)smem;             // 2 x 16KB, swizzled tiles
    unsigned short* PuS = (unsigned short*)(smem + 32768);   // 2 x 16 frag-tiles x 1KB
    float* lsumF = (float*)(smem + 65536);                   // [4][32]

    const int tid = threadIdx.x;
    const int b = blockIdx.x & 7;                            // batch -> XCD affinity
    const int q128 = (blockIdx.x >> 3) << 7;
    const int w = tid >> 6;                                  // wave 0-7 -> SIMD w&3
    const int L = tid & 63;
    const int l31 = L & 31, hi = L >> 5;
    const int x15 = l31 & 15;

    const unsigned short* Kb = Kbf + (size_t)b * NHW * NE;
    const unsigned short* Vb = Vbf + (size_t)b * NC * NHW;

    v16f o[2][4];                                            // consumer acc [ct][qt], 128 AGPR
#pragma unroll
    for (int ct = 0; ct < 2; ++ct)
#pragma unroll
        for (int qt = 0; qt < 4; ++qt)
#pragma unroll
            for (int r = 0; r < 16; ++r) o[ct][qt][r] = 0.f;
    float lacc = 0.f;                                        // producer row-sum partial

    v8bf bq[8];                                              // producer Q B-frags
    v8bf av[2][4];                                           // consumer V A-frags
    const unsigned short* vb0 = nullptr;
    const unsigned short* vb1 = nullptr;

    if (w < 4) {
        // producer prologue: Q frags + DMA K tile 0 into buf 0
        const unsigned short* qrow = Qbf + ((size_t)b * NHW + q128 + w * 32 + l31) * NE + hi * 8;
#pragma unroll
        for (int ef = 0; ef < 8; ++ef)
            bq[ef] = *(const v8bf*)(qrow + ef * 16);
#pragma unroll
        for (int jj = 0; jj < 4; ++jj) {
            int j = w * 4 + jj;
            dma16(Kb + (size_t)j * 512 + L * 8, KuS + j * 512);
        }
        WAIT_VM0();
    } else {
        // consumer prologue: V frags tile 0
        int ci = w - 4;
        vb0 = Vb + (size_t)(ci * 64 + l31) * NHW + hi * 8;
        vb1 = Vb + (size_t)(ci * 64 + 32 + l31) * NHW + hi * 8;
#pragma unroll
        for (int kf = 0; kf < 4; ++kf) {
            av[0][kf] = *(const v8bf*)(vb0 + kf * 16);
            av[1][kf] = *(const v8bf*)(vb1 + kf * 16);
        }
    }
    BARRIER_LDS();

    for (int it = 0; it < 65; ++it) {
        if (w < 4 && it < 64) {
            // ================= PRODUCER round i =================
            const int buf = it & 1;
            const int nbuf = (it + 1) & 1;
            const size_t ktn = (size_t)((it + 1) & 63) * 64;
            // DMA next K tile (drained by vmcnt(0) at round end)
#pragma unroll
            for (int jj = 0; jj < 4; ++jj) {
                int j = w * 4 + jj;
                dma16(Kb + ktn * NE + (size_t)j * 512 + L * 8, KuS + nbuf * 8192 + j * 512);
            }
            const unsigned short* kub = KuS + buf * 8192;
#pragma unroll
            for (int kt = 0; kt < 2; ++kt) {
                // QK: S^T[32k x 32q], two 4-deep chains (A=K, B=Q) -- R5-verified reads
                v16f sa, sb;
#pragma unroll
                for (int r = 0; r < 16; ++r) { sa[r] = 0.f; sb[r] = 0.f; }
                const unsigned short* krow = kub + (kt * 32 + l31) * 128;
#pragma unroll
                for (int ef = 0; ef < 4; ++ef) {
                    v8bf ak0 = *(const v8bf*)(krow + (((2 * ef + hi) ^ x15) * 8));
                    v8bf ak1 = *(const v8bf*)(krow + (((2 * (ef + 4) + hi) ^ x15) * 8));
                    sa = __builtin_amdgcn_mfma_f32_32x32x16_bf16(ak0, bq[ef], sa, 0, 0, 0);
                    sb = __builtin_amdgcn_mfma_f32_32x32x16_bf16(ak1, bq[ef + 4], sb, 0, 0, 0);
                }
                // softmax (scale*log2e folded into Q); lane owns q-col l31
                float p[16];
#pragma unroll
                for (int r = 0; r < 16; ++r) p[r] = EXP2F(sa[r] + sb[r]);
#pragma unroll
                for (int r = 0; r < 16; ++r) lacc += p[r];
                // P^T B-frags in regs (R3/R8-verified exchange)
                unsigned int pk[8], px[8];
#pragma unroll
                for (int t = 0; t < 8; ++t) pk[t] = pack_bf2_ru(p[2 * t], p[2 * t + 1]);
#pragma unroll
                for (int t = 0; t < 8; ++t) px[t] = (unsigned int)__shfl_xor((int)pk[t], 32);
                union { v4u u; v8bf bb; } f0, f1;
                if (hi == 0) {
                    f0.u = (v4u){pk[0], pk[1], px[0], px[1]};
                    f1.u = (v4u){pk[4], pk[5], px[4], px[5]};
                } else {
                    f0.u = (v4u){px[2], px[3], pk[2], pk[3]};
                    f1.u = (v4u){px[6], px[7], pk[6], pk[7]};
                }
                // share: frag-tile (qsub=w, kf=kt*2+{0,1}), unit = hi*32+l31 (lane-major,
                // conflict-free b128: consecutive lanes -> consecutive 16B)
                unsigned short* pw_ = PuS + buf * 8192 + (w * 4 + kt * 2) * 512 + (hi * 32 + l31) * 8;
                *(v4u*)pw_ = f0.u;
                *(v4u*)(pw_ + 512) = f1.u;
            }
            WAIT_VM0();                                      // DMA(i+1) landed before next round
        }
        if (w >= 4 && it > 0) {
            // ================= CONSUMER round i: PV over tile it-1 =================
            const int pbuf = (it - 1) & 1;
            const unsigned short* pb = PuS + pbuf * 8192 + (hi * 32 + l31) * 8;
#pragma unroll
            for (int qt = 0; qt < 4; ++qt) {
                v8bf bp[4];
#pragma unroll
                for (int kf = 0; kf < 4; ++kf)
                    bp[kf] = *(const v8bf*)(pb + (qt * 4 + kf) * 512);
#pragma unroll
                for (int kf = 0; kf < 4; ++kf) {
                    o[0][qt] = __builtin_amdgcn_mfma_f32_32x32x16_bf16(av[0][kf], bp[kf], o[0][qt], 0, 0, 0);
                    o[1][qt] = __builtin_amdgcn_mfma_f32_32x32x16_bf16(av[1][kf], bp[kf], o[1][qt], 0, 0, 0);
                }
            }
            // reload V frags for tile it (consumed next round; ~full round slack)
            const size_t kc0 = (size_t)(it & 63) * 64;
#pragma unroll
            for (int kf = 0; kf < 4; ++kf) {
                av[0][kf] = *(const v8bf*)(vb0 + kc0 + kf * 16);
                av[1][kf] = *(const v8bf*)(vb1 + kc0 + kf * 16);
            }
        }
        BARRIER_LDS();                                       // single round barrier
    }

    // ---- row-sum handoff: producers -> lsum -> consumers
    if (w < 4) {
        float tot = lacc + __shfl_xor(lacc, 32);
        if (hi == 0) lsumF[w * 32 + l31] = tot;
    }
    BARRIER_LDS();
    if (w >= 4) {
        const int ci = w - 4;
        float inv[4];
#pragma unroll
        for (int qt = 0; qt < 4; ++qt) inv[qt] = 1.0f / lsumF[qt * 32 + l31];
        // store: O^T C/D lane = q-col -> coalesced dwords
#pragma unroll
        for (int ct = 0; ct < 2; ++ct)
#pragma unroll
            for (int qt = 0; qt < 4; ++qt) {
                float* ob = out + (size_t)b * NC * NHW + q128 + qt * 32 + l31;
#pragma unroll
                for (int r = 0; r < 16; ++r) {
                    int c = ci * 64 + ct * 32 + (r & 3) + 8 * (r >> 2) + 4 * hi;
                    ob[(size_t)c * NHW] = o[ct][qt][r] * inv[qt];
                }
            }
    }
}

extern "C" void kernel_launch(void* const* d_in, const int* in_sizes, int n_in,
                              void* d_out, int out_size, void* d_ws, size_t ws_size,
                              hipStream_t stream) {
    const float* l  = (const float*)d_in[0];
    const float* wt = (const float*)d_in[1];
    const float* wp = (const float*)d_in[2];
    float* out = (float*)d_out;

    char* ws = (char*)d_ws;
    unsigned short* Wbf = (unsigned short*)ws;                          // 131072 B
    unsigned short* Qbf = (unsigned short*)(ws + 131072);               // 8 MB
    unsigned short* Kbf = (unsigned short*)(ws + 131072 + 8388608);     // 8 MB (pre-swizzled)
    unsigned short* Vbf = (unsigned short*)(ws + 131072 + 16777216);    // 16 MB

    hipLaunchKernelGGL(cast_w_kernel, dim3(256), dim3(256), 0, stream, wt, wp, Wbf);
    hipLaunchKernelGGL(proj_kernel,   dim3(512), dim3(256), 0, stream, l, Wbf, Qbf, Kbf, Vbf);
    hipLaunchKernelGGL(attn_kernel,   dim3(256), dim3(512), 0, stream, Qbf, Kbf, Vbf, out);
}